// Round 6
// baseline (113.214 us; speedup 1.0000x reference)
//
#include <hip/hip_runtime.h>

// FeaStConv x2, HEADS=1 => softmax==1 => layer = relu((segsum(h[src])@W)/deg + b).
// Pipeline (4 dispatches):
//   memset   : zero cnt[n] + ovf_cnt
//   k_fill   : per-dst bucket build (CAP=16 atomic append; overflow -> (src,dst) list)
//   k_gdense : per-block W1->LDS hi/lo bf16 repack, fused neighbor-gather into
//              MFMA A-fragments, 3-term bf16-split MFMA (xs@W1), relu/deg/b1,
//              W2 epilogue -> p[N,4]
//   k_out    : layer-2 gather of p + bias/relu -> out
// Overflow (deg>CAP) handled by in-kernel scan of the tiny overflow list.

#define TPB 256
#define CAP 16

typedef __attribute__((ext_vector_type(8))) short bf16x8;
typedef __attribute__((ext_vector_type(4))) float f32x4;

__device__ __forceinline__ void split_bf16(float f, ushort& hi, ushort& lo) {
    unsigned u = __float_as_uint(f);
    unsigned h = u >> 16;
    float fh = __uint_as_float(h << 16);
    float r = f - fh;                      // exact
    hi = (ushort)h;
    lo = (ushort)(__float_as_uint(r) >> 16);
}

__global__ void k_fill(const int* __restrict__ src, const int* __restrict__ dst,
                       int* __restrict__ cnt, int* __restrict__ bucket,
                       int* __restrict__ ovf_cnt, int2* __restrict__ ovf_list, int E) {
    int e = blockIdx.x * TPB + threadIdx.x;
    if (e >= E) return;
    int d = dst[e];
    int s = src[e];
    int slot = atomicAdd(&cnt[d], 1);
    if (slot < CAP) bucket[(size_t)d * CAP + slot] = s;
    else { int pos = atomicAdd(ovf_cnt, 1); ovf_list[pos] = make_int2(s, d); }
}

// 4 waves/block, wave = 16 nodes. Lane l: node r = l&15, channel octet kh = l>>4.
__global__ __launch_bounds__(256) void k_gdense(
    const float* __restrict__ x, const int* __restrict__ cnt,
    const int* __restrict__ bucket, const int* __restrict__ ovf_cnt,
    const int2* __restrict__ ovf_list, const float* __restrict__ W1,
    const float* __restrict__ b1, const float* __restrict__ W2,
    float* __restrict__ p, int n) {
    __shared__ __align__(16) ushort sHi[12800];   // 25.6 KB  [ct*64+l][8]
    __shared__ __align__(16) ushort sLo[12800];   // 25.6 KB

    // ---- per-block W1 repack into LDS (B-fragments, hi/lo split) ----
    for (int pair = threadIdx.x; pair < 1600; pair += TPB) {
        int ct = pair >> 6, l = pair & 63;
        int kh = l >> 4, c = l & 15;
#pragma unroll
        for (int e = 0; e < 8; e++) {
            // B[k][col] fragment: k = 8*kh + e, col = ct*16 + c
            float f = W1[(8 * kh + e) * 400 + ct * 16 + c];
            ushort h, lo; split_bf16(f, h, lo);
            sHi[pair * 8 + e] = h;
            sLo[pair * 8 + e] = lo;
        }
    }

    int wid = threadIdx.x >> 6, l = threadIdx.x & 63;
    int base_w = blockIdx.x * 64 + wid * 16;
    int r = l & 15, kh = l >> 4;

    int node = base_w + r; if (node > n - 1) node = n - 1;
    int m = cnt[node];
    int mb = m < CAP ? m : CAP;

    // ---- gather: self term + bucketed neighbors ----
    const float4* xp = (const float4*)(x + (size_t)node * 32 + kh * 8);
    float4 s0 = xp[0], s1 = xp[1];
    float acc[8] = {s0.x, s0.y, s0.z, s0.w, s1.x, s1.y, s1.z, s1.w};

    const int4* bkt = (const int4*)(bucket + (size_t)node * CAP);
#pragma unroll
    for (int c4 = 0; c4 < CAP / 4; c4++) {
        if (4 * c4 < mb) {
            int4 b = bkt[c4];
            int base_s = 4 * c4;
            int ids[4] = {b.x, b.y, b.z, b.w};
#pragma unroll
            for (int j = 0; j < 4; j++) {
                if (base_s + j < mb) {
                    const float4* vp = (const float4*)(x + (size_t)ids[j] * 32 + kh * 8);
                    float4 v0 = vp[0], v1 = vp[1];
                    acc[0] += v0.x; acc[1] += v0.y; acc[2] += v0.z; acc[3] += v0.w;
                    acc[4] += v1.x; acc[5] += v1.y; acc[6] += v1.z; acc[7] += v1.w;
                }
            }
        }
    }
    if (m > CAP) {                       // rare; exec-masked
        int L = ovf_cnt[0];
        for (int j = 0; j < L; j++) {
            int2 sd = ovf_list[j];
            if (sd.y == node) {
                const float4* vp = (const float4*)(x + (size_t)sd.x * 32 + kh * 8);
                float4 v0 = vp[0], v1 = vp[1];
                acc[0] += v0.x; acc[1] += v0.y; acc[2] += v0.z; acc[3] += v0.w;
                acc[4] += v1.x; acc[5] += v1.y; acc[6] += v1.z; acc[7] += v1.w;
            }
        }
    }

    bf16x8 a_hi, a_lo;
#pragma unroll
    for (int e = 0; e < 8; e++) {
        ushort h, lo; split_bf16(acc[e], h, lo);
        a_hi[e] = (short)h; a_lo[e] = (short)lo;
    }

    float invd_q[4];
#pragma unroll
    for (int q = 0; q < 4; q++) {
        int nq = base_w + kh * 4 + q; if (nq > n - 1) nq = n - 1;
        invd_q[q] = 1.0f / (float)(cnt[nq] + 1);
    }

    __syncthreads();   // LDS pack ready

    float pacc[4][4];
#pragma unroll
    for (int q = 0; q < 4; q++)
#pragma unroll
        for (int o = 0; o < 4; o++) pacc[q][o] = 0.f;

    for (int ct = 0; ct < 25; ct++) {
        bf16x8 bh = *(const bf16x8*)(sHi + ((ct * 64 + l) << 3));
        bf16x8 bl = *(const bf16x8*)(sLo + ((ct * 64 + l) << 3));
        f32x4 c = {0.f, 0.f, 0.f, 0.f};
        c = __builtin_amdgcn_mfma_f32_16x16x32_bf16(a_hi, bh, c, 0, 0, 0);
        c = __builtin_amdgcn_mfma_f32_16x16x32_bf16(a_lo, bh, c, 0, 0, 0);
        c = __builtin_amdgcn_mfma_f32_16x16x32_bf16(a_hi, bl, c, 0, 0, 0);
        float b1v = b1[ct * 16 + r];
        const float4 w2v = *(const float4*)(W2 + (size_t)(ct * 16 + r) * 4);
#pragma unroll
        for (int q = 0; q < 4; q++) {
            float h = fmaxf(fmaf(c[q], invd_q[q], b1v), 0.f);
            pacc[q][0] = fmaf(h, w2v.x, pacc[q][0]);
            pacc[q][1] = fmaf(h, w2v.y, pacc[q][1]);
            pacc[q][2] = fmaf(h, w2v.z, pacc[q][2]);
            pacc[q][3] = fmaf(h, w2v.w, pacc[q][3]);
        }
    }
#pragma unroll
    for (int mask = 1; mask <= 8; mask <<= 1)
#pragma unroll
        for (int q = 0; q < 4; q++)
#pragma unroll
            for (int o = 0; o < 4; o++)
                pacc[q][o] += __shfl_xor(pacc[q][o], mask, 64);

    if (r < 4) {
        int nd = base_w + kh * 4 + r;
        if (nd < n)
            *(float4*)(p + (size_t)nd * 4) =
                make_float4(pacc[r][0], pacc[r][1], pacc[r][2], pacc[r][3]);
    }
}

// layer-2: agg = p[node] + sum_nb p[nb]; out = relu(agg/deg + b2). 1 thread per (node,c).
__global__ void k_out(const float* __restrict__ p, const int* __restrict__ cnt,
                      const int* __restrict__ bucket, const int* __restrict__ ovf_cnt,
                      const int2* __restrict__ ovf_list,
                      const float* __restrict__ b2, float* __restrict__ out, int n) {
    int gid = blockIdx.x * blockDim.x + threadIdx.x;
    int node = gid >> 2, c = gid & 3;
    if (node >= n) return;
    int m = cnt[node];
    int mb = m < CAP ? m : CAP;
    float acc = p[(size_t)node * 4 + c];
    const int4* bkt = (const int4*)(bucket + (size_t)node * CAP);
#pragma unroll
    for (int c4 = 0; c4 < CAP / 4; c4++) {
        if (4 * c4 < mb) {
            int4 b = bkt[c4];
            int base_s = 4 * c4;
            int ids[4] = {b.x, b.y, b.z, b.w};
#pragma unroll
            for (int j = 0; j < 4; j++) {
                if (base_s + j < mb) acc += p[(size_t)ids[j] * 4 + c];
            }
        }
    }
    if (m > CAP) {
        int L = ovf_cnt[0];
        for (int j = 0; j < L; j++) {
            int2 sd = ovf_list[j];
            if (sd.y == node) acc += p[(size_t)sd.x * 4 + c];
        }
    }
    out[gid] = fmaxf(fmaf(acc, 1.0f / (float)(m + 1), b2[c]), 0.f);
}

static inline size_t align4i(size_t v) { return (v + 3) & ~(size_t)3; }

extern "C" void kernel_launch(void* const* d_in, const int* in_sizes, int n_in,
                              void* d_out, int out_size, void* d_ws, size_t ws_size,
                              hipStream_t stream) {
    const float* x  = (const float*)d_in[0];
    const int*   ei = (const int*)d_in[1];
    const float* W1 = (const float*)d_in[2];
    const float* b1 = (const float*)d_in[5];
    const float* W2 = (const float*)d_in[6];
    const float* b2 = (const float*)d_in[9];

    int n = in_sizes[0] / 32;
    int E = in_sizes[1] / 2;
    const int* src = ei;
    const int* dst = ei + E;

    // workspace layout (int units, 16B-aligned sections)
    int* wsi = (int*)d_ws;
    size_t off = 0;
    int* cnt      = wsi + off; off += n;                  // n
    int* ovf_cnt  = wsi + off; off += 1;                  // zeroed with cnt
    size_t off_ovf = align4i(off);
    int2* ovf_list = (int2*)(wsi + off_ovf); off = off_ovf + 2 * (size_t)E;
    size_t off_b  = align4i(off);
    int* bucket   = wsi + off_b;  off = off_b + (size_t)n * CAP;
    size_t off_p  = align4i(off);
    float* p      = (float*)(wsi + off_p);
    float* out    = (float*)d_out;

    hipMemsetAsync(cnt, 0, (size_t)(n + 1) * sizeof(int), stream);
    k_fill<<<(E + TPB - 1) / TPB, TPB, 0, stream>>>(src, dst, cnt, bucket,
                                                    ovf_cnt, ovf_list, E);
    k_gdense<<<(n + 63) / 64, 256, 0, stream>>>(x, cnt, bucket, ovf_cnt, ovf_list,
                                                W1, b1, W2, p, n);
    k_out<<<((size_t)n * 4 + TPB - 1) / TPB, TPB, 0, stream>>>(p, cnt, bucket,
                                                               ovf_cnt, ovf_list,
                                                               b2, out, n);
}